// Round 13
// baseline (615.222 us; speedup 1.0000x reference)
//
#include <hip/hip_runtime.h>
#include <hip/hip_bf16.h>
#include <math.h>
#include <stdint.h>

#define EPS 1e-5f
#define LEAK 0.01f
#define NEG_INF (-3.402823e38f)

typedef __attribute__((ext_vector_type(8))) short short8v;
typedef __attribute__((ext_vector_type(4))) float f32x4;

__device__ __forceinline__ float sigm(float x){ return 1.0f/(1.0f + __expf(-x)); }
__device__ __forceinline__ float tanhf_(float x){ return 1.0f - 2.0f/(__expf(2.0f*x)+1.0f); }
__device__ __forceinline__ float bnl(float a, float sc, float sh){
    float v = fmaf(a, sc, sh);
    return v < 0.0f ? LEAK*v : v;
}
__device__ __forceinline__ unsigned short f2bf(float f){
    __hip_bfloat16 h = __float2bfloat16(f);
    return *reinterpret_cast<unsigned short*>(&h);
}
__device__ __forceinline__ float bf2f(unsigned short u){
    return __uint_as_float(((unsigned)u) << 16);
}

// ---------- conv weight pack: w[3][3][CIN][COUT] f32 -> wp[(9*CIN)/8][COUT][8] bf16 ----------
__global__ __launch_bounds__(256) void pack_k(const float* __restrict__ w,
                                              unsigned short* __restrict__ wp,
                                              int CIN, int COUT){
    int t = blockIdx.x*256 + threadIdx.x;
    int total = 9*CIN*COUT;
    if (t >= total) return;
    int cout = t % COUT, k = t / COUT;
    float v = w[(size_t)k*COUT + cout];
    wp[(size_t)(k>>3)*COUT*8 + (size_t)cout*8 + (k&7)] = f2bf(v);
}

// ---------- LSTM weight pack: src[K][512] f32 -> dst[(K/8)][512][8] bf16 ----------
__global__ __launch_bounds__(256) void packW_k(const float* __restrict__ src,
                                               unsigned short* __restrict__ dst, int K){
    int t = blockIdx.x*256 + threadIdx.x;
    if (t < K*512){
        int k = t >> 9, col = t & 511;
        dst[(size_t)(k>>3)*4096 + col*8 + (k&7)] = f2bf(src[(size_t)k*512 + col]);
    }
}

// ---------- Wout pack: Wout[128][37] f32 -> WoT[37][128] bf16 ----------
__global__ __launch_bounds__(256) void packWoT_k(const float* __restrict__ src,
                                                 unsigned short* __restrict__ dst){
    int t = blockIdx.x*256 + threadIdx.x;
    if (t < 37*128){
        int n = t >> 7, k = t & 127;
        dst[t] = f2bf(src[k*37 + n]);
    }
}

// ---------- BN fold ----------
__global__ void bn_k(const float* __restrict__ cb, const float* __restrict__ g,
                     const float* __restrict__ bb, const float* __restrict__ mm,
                     const float* __restrict__ mv, float* __restrict__ sc,
                     float* __restrict__ sh, int n){
    int t = threadIdx.x;
    if (t < n){
        float s = g[t]*rsqrtf(mv[t]+EPS);
        sc[t] = s;
        sh[t] = fmaf(cb[t]-mm[t], s, bb[t]);
    }
}

// ---------- conv block 0: thread = one pooled px, all 64 couts; weights in LDS ----------
__global__ __launch_bounds__(256) void conv0_k(
    const float* __restrict__ x, const float* __restrict__ w,
    const float* __restrict__ bsc, const float* __restrict__ bsh,
    unsigned short* __restrict__ out, int bbase, int total)
{
    __shared__ float wv[576];
    __shared__ float scs[64], shs[64];
    const int tid = threadIdx.x;
    for (int i=tid;i<576;i+=256) wv[i] = w[i];
    if (tid < 64){ scs[tid]=bsc[tid]; shs[tid]=bsh[tid]; }
    __syncthreads();
    const int id = blockIdx.x*256 + tid;
    if (id >= total) return;
    const int px = id % 90; int r = id / 90; const int py = r % 30; const int b0 = r / 30;
    const float* xb = x + (size_t)(bbase+b0)*10800;
    float p[4][4];
    const int y0 = 2*py-1, xx0 = 2*px-1;
#pragma unroll
    for (int rr=0;rr<4;rr++){
        int yy=y0+rr;
#pragma unroll
        for (int cc=0;cc<4;cc++){
            int xc=xx0+cc;
            p[rr][cc] = (yy>=0&&yy<60&&xc>=0&&xc<180)? xb[yy*180+xc] : 0.f;
        }
    }
    unsigned short* ob = out + (size_t)id*64;
#pragma unroll
    for (int cg=0;cg<8;cg++){
        short8v o8;
#pragma unroll
        for (int j=0;j<8;j++){
            const int co = cg*8+j;
            float s00=0.f,s01=0.f,s10=0.f,s11=0.f;
#pragma unroll
            for (int ky=0;ky<3;ky++)
#pragma unroll
            for (int kx=0;kx<3;kx++){
                float wt = wv[(ky*3+kx)*64+co];
                s00 = fmaf(p[ky][kx],     wt, s00);
                s01 = fmaf(p[ky][kx+1],   wt, s01);
                s10 = fmaf(p[ky+1][kx],   wt, s10);
                s11 = fmaf(p[ky+1][kx+1], wt, s11);
            }
            float sc=scs[co], sh=shs[co];
            float m = fmaxf(fmaxf(bnl(s00,sc,sh),bnl(s01,sc,sh)),
                            fmaxf(bnl(s10,sc,sh),bnl(s11,sc,sh)));
            o8[j] = (short)f2bf(m);
        }
        *(short8v*)&ob[cg*8] = o8;
    }
}

// ---------- MFMA fused conv+BN+leaky+pool, 4 batches/block, cout-split waves ----------
// Tile: 4 rows x 16 cols x 4 batches. 4 waves = 2 row-pairs x 2 cout-halves.
// Per wave-iter: 8 ds_read_b128 -> 64 MFMA (8 A-frags share each B-frag).
template<int CIN,int COUT,int H,int W>
__global__ __launch_bounds__(256,2) void convmf_k(
    const unsigned short* __restrict__ in, const unsigned short* __restrict__ wp,
    const float* __restrict__ bsc, const float* __restrict__ bsh,
    unsigned short* __restrict__ out)
{
    constexpr int PH=(H+1)/2, PW=(W+1)/2;
    constexpr int HALVES = CIN/64;
    constexpr int NIT = 9*HALVES;          // BK=64 iterations
    constexpr int COUTW = COUT/2;
    constexpr int NREP = COUTW/16;
    constexpr int CH = (64*COUT)/(256*8);  // 16B chunks per thread per K-tile
    __shared__ alignas(16) unsigned short wls[2][64*COUT];

    const int tid = threadIdx.x;
    const int lane = tid & 63;
    const int wv = tid >> 6;
    const int wn = wv & 1;                 // cout-half
    const int wm = wv >> 1;                // row-pair
    const int l15 = lane & 15, l4 = lane >> 4;
    const int x0 = blockIdx.x*16, y0 = blockIdx.y*4;
    const int b0 = blockIdx.z*4;
    const unsigned short* inb = in + (size_t)b0*H*W*CIN;
    constexpr size_t BSTR = (size_t)H*W*CIN;

    // hoisted addressing: rows j=0..3 -> gy=y0+2wm-1+j, cols kx=0..2 -> gx=x0+l15+kx-1
    int rowoff[4]; bool rowok[4];
#pragma unroll
    for (int j=0;j<4;j++){
        int gy = y0 + 2*wm - 1 + j;
        rowok[j] = (unsigned)gy < (unsigned)H;
        rowoff[j] = (rowok[j] ? gy : 0) * (W*CIN);
    }
    int coloff[3]; bool colok[3];
#pragma unroll
    for (int kx=0;kx<3;kx++){
        int gx = x0 + l15 + kx - 1;
        colok[kx] = (unsigned)gx < (unsigned)W;
        coloff[kx] = (colok[kx] ? gx : 0) * CIN;
    }

    f32x4 acc[4][2][NREP];    // [bm][row][nf]
#pragma unroll
    for (int bm=0;bm<4;bm++)
#pragma unroll
    for (int m=0;m<2;m++)
#pragma unroll
    for (int n=0;n<NREP;n++) acc[bm][m][n] = f32x4{0.f,0.f,0.f,0.f};

    // W staging: direct global->LDS DMA, 16B/lane, linear (wave-uniform dest base)
    auto stageB = [&](int it, int buf){
        const unsigned short* src = wp + (size_t)(it*8)*(COUT*8);
#pragma unroll
        for (int i=0;i<CH;i++){
            const unsigned short* g = src + (size_t)(tid + i*256)*8;
            unsigned short* l = &wls[buf][((tid & ~63) + i*256)*8];
            __builtin_amdgcn_global_load_lds(
                (const __attribute__((address_space(1))) unsigned int*)(uintptr_t)g,
                (__attribute__((address_space(3))) unsigned int*)(uintptr_t)l,
                16, 0, 0);
        }
    };

    auto loadA = [&](int it, short8v (&a)[4][2][2]){   // [bm][rf][ks]
        const int tap = it / HALVES;
        const int khalf = it - tap*HALVES;
        const int ky = tap/3, kx = tap - ky*3;
        const int cin0 = khalf*64 + l4*8;
        const short8v z8 = short8v{0,0,0,0,0,0,0,0};
#pragma unroll
        for (int rf=0;rf<2;rf++){
            const int j = rf + ky;
            const bool ok = rowok[j] && colok[kx];
            const int off = rowoff[j] + coloff[kx] + cin0;
#pragma unroll
            for (int bm=0;bm<4;bm++){
                const unsigned short* p = inb + (size_t)bm*BSTR + off;
#pragma unroll
                for (int ks=0;ks<2;ks++){
                    short8v v = *(const short8v*)(p + ks*32);
                    a[bm][rf][ks] = ok ? v : z8;
                }
            }
        }
    };

    stageB(0, 0);
    __syncthreads();

    for (int it=0; it<NIT; ++it){
        if (it+1 < NIT) stageB(it+1, (it+1)&1);
        short8v a[4][2][2];
        loadA(it, a);
        const unsigned short* wb = &wls[it&1][0];
#pragma unroll
        for (int ks=0; ks<2; ++ks){
#pragma unroll
            for (int nf=0; nf<NREP; ++nf){
                short8v bfr = *(const short8v*)&wb[((ks*4+l4)*COUT + wn*COUTW + nf*16 + l15)*8];
#pragma unroll
                for (int bm=0;bm<4;bm++){
                    acc[bm][0][nf] = __builtin_amdgcn_mfma_f32_16x16x32_bf16(a[bm][0][ks], bfr, acc[bm][0][nf],0,0,0);
                    acc[bm][1][nf] = __builtin_amdgcn_mfma_f32_16x16x32_bf16(a[bm][1][ks], bfr, acc[bm][1][nf],0,0,0);
                }
            }
        }
        __syncthreads();
    }

    // epilogue: BN + leaky + 2x2 SAME maxpool + bf16 store (per batch)
    const int pr = (y0>>1) + wm;
    if (pr < PH){
        const bool r1 = (y0 + 2*wm + 1) < H;
#pragma unroll
        for (int bm=0;bm<4;bm++){
            unsigned short* ob = out + ((size_t)(b0+bm)*PH + pr)*PW*COUT;
#pragma unroll
            for (int nf=0; nf<NREP; ++nf){
                const int co = wn*COUTW + nf*16 + l15;
                const float scv = bsc[co], shv = bsh[co];
                f32x4 e = acc[bm][0][nf], o = acc[bm][1][nf];
#pragma unroll
                for (int pp=0; pp<2; ++pp){
                    const int pc = (x0>>1) + l4*2 + pp;
                    if (pc >= PW) continue;
                    const int oddcol = x0 + l4*4 + 2*pp + 1;
                    float m = bnl(e[2*pp], scv, shv);
                    if (oddcol < W) m = fmaxf(m, bnl(e[2*pp+1], scv, shv));
                    if (r1){
                        m = fmaxf(m, bnl(o[2*pp], scv, shv));
                        if (oddcol < W) m = fmaxf(m, bnl(o[2*pp+1], scv, shv));
                    }
                    ob[(size_t)pc*COUT + co] = f2bf(m);
                }
            }
        }
    }
}

// ---------- MFMA row-GEMM: out[3072][512] = A @ W + bias ----------
template<int K, int MODE>
__global__ __launch_bounds__(256) void gemmrow_k(
    const unsigned short* __restrict__ A, const unsigned short* __restrict__ wp,
    const float* __restrict__ bias, float* __restrict__ out)
{
    constexpr int NS = K/32;
    __shared__ alignas(16) unsigned short wls[2][16384];
    const int tid = threadIdx.x, lane = tid & 63, w = tid >> 6;
    const int l15 = lane & 15, l4 = lane >> 4;
    const int r0 = blockIdx.x*64;

    f32x4 acc[4][8];
#pragma unroll
    for (int m=0;m<4;m++)
#pragma unroll
    for (int n=0;n<8;n++) acc[m][n] = f32x4{0.f,0.f,0.f,0.f};

    auto stage = [&](int s, int buf){
        const unsigned short* src = wp + (size_t)s*16384;
#pragma unroll
        for (int i=0;i<8;i++){
            int e = (tid + i*256)*8;
            *(short8v*)&wls[buf][e] = *(const short8v*)&src[e];
        }
    };
    stage(0,0);
    __syncthreads();

    for (int s=0;s<NS;++s){
        const int k0 = s*32 + l4*8;
        short8v af[4];
#pragma unroll
        for (int mf=0;mf<4;++mf){
            const int row = r0 + mf*16 + l15;
            size_t idx;
            if constexpr (MODE == 0){
                const int b = row & 255, t = row >> 8;
                idx = (size_t)b*3072 + (k0>>6)*768 + t*64 + (k0&63);
            } else {
                idx = (size_t)row*K + k0;
            }
            af[mf] = *(const short8v*)&A[idx];
        }
        if (s+1 < NS) stage(s+1,(s+1)&1);
        const unsigned short* wb = &wls[s&1][0];
#pragma unroll
        for (int nf=0;nf<8;++nf){
            const int col = w*128 + nf*16 + l15;
            short8v bfr = *(const short8v*)&wb[(l4*512 + col)*8];
#pragma unroll
            for (int mf=0;mf<4;++mf)
                acc[mf][nf] = __builtin_amdgcn_mfma_f32_16x16x32_bf16(af[mf], bfr, acc[mf][nf], 0,0,0);
        }
        __syncthreads();
    }
#pragma unroll
    for (int nf=0;nf<8;++nf){
        const int col = w*128 + nf*16 + l15;
        const float bv = bias[col];
#pragma unroll
        for (int mf=0;mf<4;++mf){
#pragma unroll
            for (int j=0;j<4;++j){
                const int row = r0 + mf*16 + l4*4 + j;
                out[(size_t)row*512 + col] = acc[mf][nf][j] + bv;
            }
        }
    }
}

// ---------- layer-0 LSTM: Wh0 LDS-resident, 256 blocks x 1 batch ----------
__global__ __launch_bounds__(512) void lstm0_k(
    const float* __restrict__ xp, const unsigned short* __restrict__ wh0p,
    unsigned short* __restrict__ h0g)
{
    __shared__ alignas(16) unsigned short wl[65536];   // 128 KB
    __shared__ alignas(16) float hb[128];
    __shared__ float zs[512];
    const int col = threadIdx.x;
    const int b = blockIdx.x;
#pragma unroll
    for (int i=0;i<16;i++){
        int e = (col + i*512)*8;
        *(short8v*)&wl[e] = *(const short8v*)&wh0p[e];
    }
    if (col < 128) hb[col] = 0.f;
    float c0 = 0.f;
    __syncthreads();

    for (int t=0;t<12;t++){
        float acc = xp[((size_t)t*256 + b)*512 + col];
#pragma unroll 4
        for (int kg=0;kg<16;kg++){
            short8v w8 = *(const short8v*)&wl[(kg*512 + col)*8];
            float4 hlo = *(const float4*)&hb[kg*8];
            float4 hhi = *(const float4*)&hb[kg*8+4];
            acc = fmaf(bf2f((unsigned short)w8[0]), hlo.x, acc);
            acc = fmaf(bf2f((unsigned short)w8[1]), hlo.y, acc);
            acc = fmaf(bf2f((unsigned short)w8[2]), hlo.z, acc);
            acc = fmaf(bf2f((unsigned short)w8[3]), hlo.w, acc);
            acc = fmaf(bf2f((unsigned short)w8[4]), hhi.x, acc);
            acc = fmaf(bf2f((unsigned short)w8[5]), hhi.y, acc);
            acc = fmaf(bf2f((unsigned short)w8[6]), hhi.z, acc);
            acc = fmaf(bf2f((unsigned short)w8[7]), hhi.w, acc);
        }
        zs[col] = acc;
        __syncthreads();
        if (col < 128){
            float zi=zs[col], zj=zs[128+col], zf=zs[256+col], zo=zs[384+col];
            c0 = c0*sigm(zf+1.f) + sigm(zi)*tanhf_(zj);
            float h = tanhf_(c0)*sigm(zo);
            hb[col] = h;
            h0g[((size_t)t*256 + b)*128 + col] = f2bf(h);
        }
        __syncthreads();
    }
}

// ---------- layer-1 LSTM + projection: Wh1 LDS-resident, 256 blocks x 1 batch ----------
__global__ __launch_bounds__(512) void lstm1_k(
    const float* __restrict__ zp1, const unsigned short* __restrict__ wh1p,
    const unsigned short* __restrict__ woT, const float* __restrict__ bout,
    float* __restrict__ out)
{
    __shared__ alignas(16) unsigned short wl[65536];   // 128 KB
    __shared__ alignas(16) float hb[128];
    __shared__ float zs[512];
    __shared__ float red[37][8];
    const int col = threadIdx.x;
    const int b = blockIdx.x;
#pragma unroll
    for (int i=0;i<16;i++){
        int e = (col + i*512)*8;
        *(short8v*)&wl[e] = *(const short8v*)&wh1p[e];
    }
    if (col < 128) hb[col] = 0.f;
    float c1 = 0.f;
    __syncthreads();

    for (int t=0;t<12;t++){
        float acc = zp1[((size_t)t*256 + b)*512 + col];
#pragma unroll 4
        for (int kg=0;kg<16;kg++){
            short8v w8 = *(const short8v*)&wl[(kg*512 + col)*8];
            float4 hlo = *(const float4*)&hb[kg*8];
            float4 hhi = *(const float4*)&hb[kg*8+4];
            acc = fmaf(bf2f((unsigned short)w8[0]), hlo.x, acc);
            acc = fmaf(bf2f((unsigned short)w8[1]), hlo.y, acc);
            acc = fmaf(bf2f((unsigned short)w8[2]), hlo.z, acc);
            acc = fmaf(bf2f((unsigned short)w8[3]), hlo.w, acc);
            acc = fmaf(bf2f((unsigned short)w8[4]), hhi.x, acc);
            acc = fmaf(bf2f((unsigned short)w8[5]), hhi.y, acc);
            acc = fmaf(bf2f((unsigned short)w8[6]), hhi.z, acc);
            acc = fmaf(bf2f((unsigned short)w8[7]), hhi.w, acc);
        }
        zs[col] = acc;
        __syncthreads();
        if (col < 128){
            float zi=zs[col], zj=zs[128+col], zf=zs[256+col], zo=zs[384+col];
            c1 = c1*sigm(zf+1.f) + sigm(zi)*tanhf_(zj);
            hb[col] = tanhf_(c1)*sigm(zo);
        }
        __syncthreads();
        if (col < 296){
            const int n = col >> 3, q = col & 7;
            float p0 = 0.f;
#pragma unroll
            for (int kk=0;kk<16;kk++){
                float wv2 = bf2f(woT[n*128 + q*16 + kk]);
                p0 = fmaf(hb[q*16+kk], wv2, p0);
            }
            red[n][q] = p0;
        }
        __syncthreads();
        if (col < 37){
            float s0 = bout[col];
#pragma unroll
            for (int q=0;q<8;q++) s0 += red[col][q];
            out[((size_t)t*256 + b)*37 + col] = s0;
        }
        __syncthreads();
    }
}

extern "C" void kernel_launch(void* const* d_in, const int* in_sizes, int n_in,
                              void* d_out, int out_size, void* d_ws, size_t ws_size,
                              hipStream_t stream) {
    const float* x = (const float*)d_in[0];
    const float *w_[4], *cb_[4], *g_[4], *bb_[4], *mm_[4], *mv_[4];
    for (int i=0;i<4;i++){
        w_[i]  = (const float*)d_in[1+6*i];
        cb_[i] = (const float*)d_in[2+6*i];
        g_[i]  = (const float*)d_in[3+6*i];
        bb_[i] = (const float*)d_in[4+6*i];
        mm_[i] = (const float*)d_in[5+6*i];
        mv_[i] = (const float*)d_in[6+6*i];
    }
    const float* lW0  = (const float*)d_in[25];
    const float* lb0  = (const float*)d_in[26];
    const float* lW1  = (const float*)d_in[27];
    const float* lb1  = (const float*)d_in[28];
    const float* Wout = (const float*)d_in[29];
    const float* bout = (const float*)d_in[30];
    float* out = (float*)d_out;

    const size_t fixed = 6291456ull + 6291456 + 4096 + 1572864 + 786432
                       + 147456 + 294912 + 147456
                       + 262144 + 131072 + 131072 + 131072 + 9472;
    int Bc = 256;
    while (Bc > 8 && fixed + (size_t)Bc*565504 > ws_size) Bc >>= 1;

    char* cur = (char*)d_ws;
    float* XP  = (float*)cur;                    cur += 6291456;
    float* ZP1 = (float*)cur;                    cur += 6291456;
    float* bns = (float*)cur;                    cur += 4096;
    unsigned short* F    = (unsigned short*)cur; cur += 1572864;
    unsigned short* h0g  = (unsigned short*)cur; cur += 786432;
    unsigned short* Wp1  = (unsigned short*)cur; cur += 147456;
    unsigned short* Wp2  = (unsigned short*)cur; cur += 294912;
    unsigned short* Wp3  = (unsigned short*)cur; cur += 147456;
    unsigned short* Wx0p = (unsigned short*)cur; cur += 262144;
    unsigned short* Wh0p = (unsigned short*)cur; cur += 131072;
    unsigned short* Wx1p = (unsigned short*)cur; cur += 131072;
    unsigned short* Wh1p = (unsigned short*)cur; cur += 131072;
    unsigned short* WoT  = (unsigned short*)cur; cur += 9472;
    unsigned short* A    = (unsigned short*)cur; cur += (size_t)Bc*345600;
    unsigned short* Bb   = (unsigned short*)cur; cur += (size_t)Bc*172800;
    unsigned short* C    = (unsigned short*)cur;

    pack_k<<<(9*64*128+255)/256, 256, 0, stream>>>(w_[1], Wp1, 64, 128);
    pack_k<<<(9*128*128+255)/256, 256, 0, stream>>>(w_[2], Wp2, 128, 128);
    pack_k<<<(9*128*64+255)/256, 256, 0, stream>>>(w_[3], Wp3, 128, 64);
    packW_k<<<512, 256, 0, stream>>>(lW0,           Wx0p, 256);
    packW_k<<<256, 256, 0, stream>>>(lW0 + 256*512, Wh0p, 128);
    packW_k<<<256, 256, 0, stream>>>(lW1,           Wx1p, 128);
    packW_k<<<256, 256, 0, stream>>>(lW1 + 128*512, Wh1p, 128);
    packWoT_k<<<19, 256, 0, stream>>>(Wout, WoT);
    bn_k<<<1,128,0,stream>>>(cb_[1],g_[1],bb_[1],mm_[1],mv_[1], bns+0,   bns+128, 128);
    bn_k<<<1,128,0,stream>>>(cb_[2],g_[2],bb_[2],mm_[2],mv_[2], bns+256, bns+384, 128);
    bn_k<<<1,64 ,0,stream>>>(cb_[3],g_[3],bb_[3],mm_[3],mv_[3], bns+512, bns+576, 64);
    bn_k<<<1,64 ,0,stream>>>(cb_[0],g_[0],bb_[0],mm_[0],mv_[0], bns+640, bns+704, 64);

    const int nc = 256 / Bc;
    for (int bc=0; bc<nc; bc++){
        int bbase = bc*Bc;
        conv0_k<<<(Bc*2700+255)/256, 256, 0, stream>>>(x, w_[0], bns+640, bns+704, A, bbase, Bc*2700);
        // 4 batches per block: z = Bc/4
        convmf_k<64,128,30,90><<<dim3(6,8,Bc/4), 256, 0, stream>>>(A, Wp1, bns+0, bns+128, Bb);
        convmf_k<128,128,15,45><<<dim3(3,4,Bc/4), 256, 0, stream>>>(Bb, Wp2, bns+256, bns+384, C);
        convmf_k<128,64,8,23><<<dim3(2,2,Bc/4), 256, 0, stream>>>(C, Wp3, bns+512, bns+576,
                                                                  F + (size_t)bbase*3072);
    }
    gemmrow_k<256,0><<<48, 256, 0, stream>>>(F, Wx0p, lb0, XP);
    lstm0_k<<<256, 512, 0, stream>>>(XP, Wh0p, h0g);
    gemmrow_k<128,1><<<48, 256, 0, stream>>>(h0g, Wx1p, lb1, ZP1);
    lstm1_k<<<256, 512, 0, stream>>>(ZP1, Wh1p, WoT, bout, out);
}

// Round 14
// 435.485 us; speedup vs baseline: 1.4127x; 1.4127x over previous
//
#include <hip/hip_runtime.h>
#include <hip/hip_bf16.h>
#include <math.h>
#include <stdint.h>

#define EPS 1e-5f
#define LEAK 0.01f
#define NEG_INF (-3.402823e38f)

typedef __attribute__((ext_vector_type(8))) short short8v;
typedef __attribute__((ext_vector_type(4))) float f32x4;

__device__ __forceinline__ float sigm(float x){ return 1.0f/(1.0f + __expf(-x)); }
__device__ __forceinline__ float tanhf_(float x){ return 1.0f - 2.0f/(__expf(2.0f*x)+1.0f); }
__device__ __forceinline__ float bnl(float a, float sc, float sh){
    float v = fmaf(a, sc, sh);
    return v < 0.0f ? LEAK*v : v;
}
__device__ __forceinline__ unsigned short f2bf(float f){
    __hip_bfloat16 h = __float2bfloat16(f);
    return *reinterpret_cast<unsigned short*>(&h);
}
__device__ __forceinline__ float bf2f(unsigned short u){
    return __uint_as_float(((unsigned)u) << 16);
}

// ---------- conv weight pack: w[3][3][CIN][COUT] f32 -> wp[(9*CIN)/8][COUT][8] bf16 ----------
__global__ __launch_bounds__(256) void pack_k(const float* __restrict__ w,
                                              unsigned short* __restrict__ wp,
                                              int CIN, int COUT){
    int t = blockIdx.x*256 + threadIdx.x;
    int total = 9*CIN*COUT;
    if (t >= total) return;
    int cout = t % COUT, k = t / COUT;
    float v = w[(size_t)k*COUT + cout];
    wp[(size_t)(k>>3)*COUT*8 + (size_t)cout*8 + (k&7)] = f2bf(v);
}

// ---------- LSTM weight pack: src[K][512] f32 -> dst[(K/8)][512][8] bf16 ----------
__global__ __launch_bounds__(256) void packW_k(const float* __restrict__ src,
                                               unsigned short* __restrict__ dst, int K){
    int t = blockIdx.x*256 + threadIdx.x;
    if (t < K*512){
        int k = t >> 9, col = t & 511;
        dst[(size_t)(k>>3)*4096 + col*8 + (k&7)] = f2bf(src[(size_t)k*512 + col]);
    }
}

// ---------- Wout pack: Wout[128][37] f32 -> WoT[37][128] bf16 ----------
__global__ __launch_bounds__(256) void packWoT_k(const float* __restrict__ src,
                                                 unsigned short* __restrict__ dst){
    int t = blockIdx.x*256 + threadIdx.x;
    if (t < 37*128){
        int n = t >> 7, k = t & 127;
        dst[t] = f2bf(src[k*37 + n]);
    }
}

// ---------- BN fold ----------
__global__ void bn_k(const float* __restrict__ cb, const float* __restrict__ g,
                     const float* __restrict__ bb, const float* __restrict__ mm,
                     const float* __restrict__ mv, float* __restrict__ sc,
                     float* __restrict__ sh, int n){
    int t = threadIdx.x;
    if (t < n){
        float s = g[t]*rsqrtf(mv[t]+EPS);
        sc[t] = s;
        sh[t] = fmaf(cb[t]-mm[t], s, bb[t]);
    }
}

// ---------- conv block 0: thread = one pooled px, all 64 couts; weights in LDS ----------
__global__ __launch_bounds__(256) void conv0_k(
    const float* __restrict__ x, const float* __restrict__ w,
    const float* __restrict__ bsc, const float* __restrict__ bsh,
    unsigned short* __restrict__ out, int bbase, int total)
{
    __shared__ float wv[576];
    __shared__ float scs[64], shs[64];
    const int tid = threadIdx.x;
    for (int i=tid;i<576;i+=256) wv[i] = w[i];
    if (tid < 64){ scs[tid]=bsc[tid]; shs[tid]=bsh[tid]; }
    __syncthreads();
    const int id = blockIdx.x*256 + tid;
    if (id >= total) return;
    const int px = id % 90; int r = id / 90; const int py = r % 30; const int b0 = r / 30;
    const float* xb = x + (size_t)(bbase+b0)*10800;
    float p[4][4];
    const int y0 = 2*py-1, xx0 = 2*px-1;
#pragma unroll
    for (int rr=0;rr<4;rr++){
        int yy=y0+rr;
#pragma unroll
        for (int cc=0;cc<4;cc++){
            int xc=xx0+cc;
            p[rr][cc] = (yy>=0&&yy<60&&xc>=0&&xc<180)? xb[yy*180+xc] : 0.f;
        }
    }
    unsigned short* ob = out + (size_t)id*64;
#pragma unroll
    for (int cg=0;cg<8;cg++){
        short8v o8;
#pragma unroll
        for (int j=0;j<8;j++){
            const int co = cg*8+j;
            float s00=0.f,s01=0.f,s10=0.f,s11=0.f;
#pragma unroll
            for (int ky=0;ky<3;ky++)
#pragma unroll
            for (int kx=0;kx<3;kx++){
                float wt = wv[(ky*3+kx)*64+co];
                s00 = fmaf(p[ky][kx],     wt, s00);
                s01 = fmaf(p[ky][kx+1],   wt, s01);
                s10 = fmaf(p[ky+1][kx],   wt, s10);
                s11 = fmaf(p[ky+1][kx+1], wt, s11);
            }
            float sc=scs[co], sh=shs[co];
            float m = fmaxf(fmaxf(bnl(s00,sc,sh),bnl(s01,sc,sh)),
                            fmaxf(bnl(s10,sc,sh),bnl(s11,sc,sh)));
            o8[j] = (short)f2bf(m);
        }
        *(short8v*)&ob[cg*8] = o8;
    }
}

// ---------- MFMA fused conv+BN+leaky+pool: light schedule for high occupancy ----------
// Tile: 8 rows x 16 cols x 1 batch. 4 waves = 4 row-pairs, full COUT per wave.
// JIT A-loads (no prefetch regs): unified VGPR+AGPR ~115 -> 4 waves/SIMD.
template<int CIN,int COUT,int H,int W>
__global__ __launch_bounds__(256,4) void convmf_k(
    const unsigned short* __restrict__ in, const unsigned short* __restrict__ wp,
    const float* __restrict__ bsc, const float* __restrict__ bsh,
    unsigned short* __restrict__ out)
{
    constexpr int PH=(H+1)/2, PW=(W+1)/2;
    constexpr int HALVES = CIN/64;
    constexpr int NIT = 9*HALVES;          // BK=64 iterations
    constexpr int NREP = COUT/16;
    constexpr int CH = (64*COUT)/(256*8);  // 16B chunks per thread per K-tile
    __shared__ alignas(16) unsigned short wls[2][64*COUT];

    const int tid = threadIdx.x;
    const int lane = tid & 63;
    const int wm = tid >> 6;               // row-pair
    const int l15 = lane & 15, l4 = lane >> 4;
    const int x0 = blockIdx.x*16, y0 = blockIdx.y*8;
    const int b = blockIdx.z;
    const unsigned short* inb = in + (size_t)b*H*W*CIN;

    // hoisted addressing: rows j=0..3 -> gy=y0+2wm-1+j, cols kx=0..2 -> gx=x0+l15+kx-1
    int rowoff[4]; bool rowok[4];
#pragma unroll
    for (int j=0;j<4;j++){
        int gy = y0 + 2*wm - 1 + j;
        rowok[j] = (unsigned)gy < (unsigned)H;
        rowoff[j] = (rowok[j] ? gy : 0) * (W*CIN);
    }
    int coloff[3]; bool colok[3];
#pragma unroll
    for (int kx=0;kx<3;kx++){
        int gx = x0 + l15 + kx - 1;
        colok[kx] = (unsigned)gx < (unsigned)W;
        coloff[kx] = (colok[kx] ? gx : 0) * CIN;
    }

    f32x4 acc[2][NREP];    // [row][nf]
#pragma unroll
    for (int m=0;m<2;m++)
#pragma unroll
    for (int n=0;n<NREP;n++) acc[m][n] = f32x4{0.f,0.f,0.f,0.f};

    // W staging: direct global->LDS DMA, 16B/lane, linear (wave-uniform dest base)
    auto stageB = [&](int it, int buf){
        const unsigned short* src = wp + (size_t)(it*8)*(COUT*8);
#pragma unroll
        for (int i=0;i<CH;i++){
            const unsigned short* g = src + (size_t)(tid + i*256)*8;
            unsigned short* l = &wls[buf][((tid & ~63) + i*256)*8];
            __builtin_amdgcn_global_load_lds(
                (const __attribute__((address_space(1))) unsigned int*)(uintptr_t)g,
                (__attribute__((address_space(3))) unsigned int*)(uintptr_t)l,
                16, 0, 0);
        }
    };

    stageB(0, 0);
    __syncthreads();

    for (int it=0; it<NIT; ++it){
        if (it+1 < NIT) stageB(it+1, (it+1)&1);
        // JIT A-load for this K-tile
        const int tap = it / HALVES;
        const int khalf = it - tap*HALVES;
        const int ky = tap/3, kx = tap - ky*3;
        const int cin0 = khalf*64 + l4*8;
        const short8v z8 = short8v{0,0,0,0,0,0,0,0};
        short8v a[2][2];
#pragma unroll
        for (int rf=0;rf<2;rf++){
            const int j = rf + ky;
            const bool ok = rowok[j] && colok[kx];
            const unsigned short* p = inb + rowoff[j] + coloff[kx] + cin0;
#pragma unroll
            for (int ks=0;ks<2;ks++){
                short8v v = *(const short8v*)(p + ks*32);
                a[rf][ks] = ok ? v : z8;
            }
        }
        const unsigned short* wb = &wls[it&1][0];
#pragma unroll
        for (int ks=0; ks<2; ++ks){
#pragma unroll
            for (int nf=0; nf<NREP; ++nf){
                short8v bfr = *(const short8v*)&wb[((ks*4+l4)*COUT + nf*16 + l15)*8];
                acc[0][nf] = __builtin_amdgcn_mfma_f32_16x16x32_bf16(a[0][ks], bfr, acc[0][nf],0,0,0);
                acc[1][nf] = __builtin_amdgcn_mfma_f32_16x16x32_bf16(a[1][ks], bfr, acc[1][nf],0,0,0);
            }
        }
        __syncthreads();
    }

    // epilogue: BN + leaky + 2x2 SAME maxpool + bf16 store
    const int pr = (y0>>1) + wm;
    if (pr < PH){
        const bool r1 = (y0 + 2*wm + 1) < H;
        unsigned short* ob = out + ((size_t)b*PH + pr)*PW*COUT;
#pragma unroll
        for (int nf=0; nf<NREP; ++nf){
            const int co = nf*16 + l15;
            const float scv = bsc[co], shv = bsh[co];
            f32x4 e = acc[0][nf], o = acc[1][nf];
#pragma unroll
            for (int pp=0; pp<2; ++pp){
                const int pc = (x0>>1) + l4*2 + pp;
                if (pc >= PW) continue;
                const int oddcol = x0 + l4*4 + 2*pp + 1;
                float m = bnl(e[2*pp], scv, shv);
                if (oddcol < W) m = fmaxf(m, bnl(e[2*pp+1], scv, shv));
                if (r1){
                    m = fmaxf(m, bnl(o[2*pp], scv, shv));
                    if (oddcol < W) m = fmaxf(m, bnl(o[2*pp+1], scv, shv));
                }
                ob[(size_t)pc*COUT + co] = f2bf(m);
            }
        }
    }
}

// ---------- MFMA row-GEMM: out[3072][512] = A @ W + bias ----------
template<int K, int MODE>
__global__ __launch_bounds__(256) void gemmrow_k(
    const unsigned short* __restrict__ A, const unsigned short* __restrict__ wp,
    const float* __restrict__ bias, float* __restrict__ out)
{
    constexpr int NS = K/32;
    __shared__ alignas(16) unsigned short wls[2][16384];
    const int tid = threadIdx.x, lane = tid & 63, w = tid >> 6;
    const int l15 = lane & 15, l4 = lane >> 4;
    const int r0 = blockIdx.x*64;

    f32x4 acc[4][8];
#pragma unroll
    for (int m=0;m<4;m++)
#pragma unroll
    for (int n=0;n<8;n++) acc[m][n] = f32x4{0.f,0.f,0.f,0.f};

    auto stage = [&](int s, int buf){
        const unsigned short* src = wp + (size_t)s*16384;
#pragma unroll
        for (int i=0;i<8;i++){
            int e = (tid + i*256)*8;
            *(short8v*)&wls[buf][e] = *(const short8v*)&src[e];
        }
    };
    stage(0,0);
    __syncthreads();

    for (int s=0;s<NS;++s){
        const int k0 = s*32 + l4*8;
        short8v af[4];
#pragma unroll
        for (int mf=0;mf<4;++mf){
            const int row = r0 + mf*16 + l15;
            size_t idx;
            if constexpr (MODE == 0){
                const int b = row & 255, t = row >> 8;
                idx = (size_t)b*3072 + (k0>>6)*768 + t*64 + (k0&63);
            } else {
                idx = (size_t)row*K + k0;
            }
            af[mf] = *(const short8v*)&A[idx];
        }
        if (s+1 < NS) stage(s+1,(s+1)&1);
        const unsigned short* wb = &wls[s&1][0];
#pragma unroll
        for (int nf=0;nf<8;++nf){
            const int col = w*128 + nf*16 + l15;
            short8v bfr = *(const short8v*)&wb[(l4*512 + col)*8];
#pragma unroll
            for (int mf=0;mf<4;++mf)
                acc[mf][nf] = __builtin_amdgcn_mfma_f32_16x16x32_bf16(af[mf], bfr, acc[mf][nf], 0,0,0);
        }
        __syncthreads();
    }
#pragma unroll
    for (int nf=0;nf<8;++nf){
        const int col = w*128 + nf*16 + l15;
        const float bv = bias[col];
#pragma unroll
        for (int mf=0;mf<4;++mf){
#pragma unroll
            for (int j=0;j<4;++j){
                const int row = r0 + mf*16 + l4*4 + j;
                out[(size_t)row*512 + col] = acc[mf][nf][j] + bv;
            }
        }
    }
}

// ---------- layer-0 LSTM: Wh0 LDS-resident, 256 blocks x 1 batch ----------
__global__ __launch_bounds__(512) void lstm0_k(
    const float* __restrict__ xp, const unsigned short* __restrict__ wh0p,
    unsigned short* __restrict__ h0g)
{
    __shared__ alignas(16) unsigned short wl[65536];   // 128 KB
    __shared__ alignas(16) float hb[128];
    __shared__ float zs[512];
    const int col = threadIdx.x;
    const int b = blockIdx.x;
#pragma unroll
    for (int i=0;i<16;i++){
        int e = (col + i*512)*8;
        *(short8v*)&wl[e] = *(const short8v*)&wh0p[e];
    }
    if (col < 128) hb[col] = 0.f;
    float c0 = 0.f;
    __syncthreads();

    for (int t=0;t<12;t++){
        float acc = xp[((size_t)t*256 + b)*512 + col];
#pragma unroll 4
        for (int kg=0;kg<16;kg++){
            short8v w8 = *(const short8v*)&wl[(kg*512 + col)*8];
            float4 hlo = *(const float4*)&hb[kg*8];
            float4 hhi = *(const float4*)&hb[kg*8+4];
            acc = fmaf(bf2f((unsigned short)w8[0]), hlo.x, acc);
            acc = fmaf(bf2f((unsigned short)w8[1]), hlo.y, acc);
            acc = fmaf(bf2f((unsigned short)w8[2]), hlo.z, acc);
            acc = fmaf(bf2f((unsigned short)w8[3]), hlo.w, acc);
            acc = fmaf(bf2f((unsigned short)w8[4]), hhi.x, acc);
            acc = fmaf(bf2f((unsigned short)w8[5]), hhi.y, acc);
            acc = fmaf(bf2f((unsigned short)w8[6]), hhi.z, acc);
            acc = fmaf(bf2f((unsigned short)w8[7]), hhi.w, acc);
        }
        zs[col] = acc;
        __syncthreads();
        if (col < 128){
            float zi=zs[col], zj=zs[128+col], zf=zs[256+col], zo=zs[384+col];
            c0 = c0*sigm(zf+1.f) + sigm(zi)*tanhf_(zj);
            float h = tanhf_(c0)*sigm(zo);
            hb[col] = h;
            h0g[((size_t)t*256 + b)*128 + col] = f2bf(h);
        }
        __syncthreads();
    }
}

// ---------- layer-1 LSTM + projection: Wh1 LDS-resident, 256 blocks x 1 batch ----------
__global__ __launch_bounds__(512) void lstm1_k(
    const float* __restrict__ zp1, const unsigned short* __restrict__ wh1p,
    const unsigned short* __restrict__ woT, const float* __restrict__ bout,
    float* __restrict__ out)
{
    __shared__ alignas(16) unsigned short wl[65536];   // 128 KB
    __shared__ alignas(16) float hb[128];
    __shared__ float zs[512];
    __shared__ float red[37][8];
    const int col = threadIdx.x;
    const int b = blockIdx.x;
#pragma unroll
    for (int i=0;i<16;i++){
        int e = (col + i*512)*8;
        *(short8v*)&wl[e] = *(const short8v*)&wh1p[e];
    }
    if (col < 128) hb[col] = 0.f;
    float c1 = 0.f;
    __syncthreads();

    for (int t=0;t<12;t++){
        float acc = zp1[((size_t)t*256 + b)*512 + col];
#pragma unroll 4
        for (int kg=0;kg<16;kg++){
            short8v w8 = *(const short8v*)&wl[(kg*512 + col)*8];
            float4 hlo = *(const float4*)&hb[kg*8];
            float4 hhi = *(const float4*)&hb[kg*8+4];
            acc = fmaf(bf2f((unsigned short)w8[0]), hlo.x, acc);
            acc = fmaf(bf2f((unsigned short)w8[1]), hlo.y, acc);
            acc = fmaf(bf2f((unsigned short)w8[2]), hlo.z, acc);
            acc = fmaf(bf2f((unsigned short)w8[3]), hlo.w, acc);
            acc = fmaf(bf2f((unsigned short)w8[4]), hhi.x, acc);
            acc = fmaf(bf2f((unsigned short)w8[5]), hhi.y, acc);
            acc = fmaf(bf2f((unsigned short)w8[6]), hhi.z, acc);
            acc = fmaf(bf2f((unsigned short)w8[7]), hhi.w, acc);
        }
        zs[col] = acc;
        __syncthreads();
        if (col < 128){
            float zi=zs[col], zj=zs[128+col], zf=zs[256+col], zo=zs[384+col];
            c1 = c1*sigm(zf+1.f) + sigm(zi)*tanhf_(zj);
            hb[col] = tanhf_(c1)*sigm(zo);
        }
        __syncthreads();
        if (col < 296){
            const int n = col >> 3, q = col & 7;
            float p0 = 0.f;
#pragma unroll
            for (int kk=0;kk<16;kk++){
                float wv2 = bf2f(woT[n*128 + q*16 + kk]);
                p0 = fmaf(hb[q*16+kk], wv2, p0);
            }
            red[n][q] = p0;
        }
        __syncthreads();
        if (col < 37){
            float s0 = bout[col];
#pragma unroll
            for (int q=0;q<8;q++) s0 += red[col][q];
            out[((size_t)t*256 + b)*37 + col] = s0;
        }
        __syncthreads();
    }
}

extern "C" void kernel_launch(void* const* d_in, const int* in_sizes, int n_in,
                              void* d_out, int out_size, void* d_ws, size_t ws_size,
                              hipStream_t stream) {
    const float* x = (const float*)d_in[0];
    const float *w_[4], *cb_[4], *g_[4], *bb_[4], *mm_[4], *mv_[4];
    for (int i=0;i<4;i++){
        w_[i]  = (const float*)d_in[1+6*i];
        cb_[i] = (const float*)d_in[2+6*i];
        g_[i]  = (const float*)d_in[3+6*i];
        bb_[i] = (const float*)d_in[4+6*i];
        mm_[i] = (const float*)d_in[5+6*i];
        mv_[i] = (const float*)d_in[6+6*i];
    }
    const float* lW0  = (const float*)d_in[25];
    const float* lb0  = (const float*)d_in[26];
    const float* lW1  = (const float*)d_in[27];
    const float* lb1  = (const float*)d_in[28];
    const float* Wout = (const float*)d_in[29];
    const float* bout = (const float*)d_in[30];
    float* out = (float*)d_out;

    const size_t fixed = 6291456ull + 6291456 + 4096 + 1572864 + 786432
                       + 147456 + 294912 + 147456
                       + 262144 + 131072 + 131072 + 131072 + 9472;
    int Bc = 256;
    while (Bc > 8 && fixed + (size_t)Bc*565504 > ws_size) Bc >>= 1;

    char* cur = (char*)d_ws;
    float* XP  = (float*)cur;                    cur += 6291456;
    float* ZP1 = (float*)cur;                    cur += 6291456;
    float* bns = (float*)cur;                    cur += 4096;
    unsigned short* F    = (unsigned short*)cur; cur += 1572864;
    unsigned short* h0g  = (unsigned short*)cur; cur += 786432;
    unsigned short* Wp1  = (unsigned short*)cur; cur += 147456;
    unsigned short* Wp2  = (unsigned short*)cur; cur += 294912;
    unsigned short* Wp3  = (unsigned short*)cur; cur += 147456;
    unsigned short* Wx0p = (unsigned short*)cur; cur += 262144;
    unsigned short* Wh0p = (unsigned short*)cur; cur += 131072;
    unsigned short* Wx1p = (unsigned short*)cur; cur += 131072;
    unsigned short* Wh1p = (unsigned short*)cur; cur += 131072;
    unsigned short* WoT  = (unsigned short*)cur; cur += 9472;
    unsigned short* A    = (unsigned short*)cur; cur += (size_t)Bc*345600;
    unsigned short* Bb   = (unsigned short*)cur; cur += (size_t)Bc*172800;
    unsigned short* C    = (unsigned short*)cur;

    pack_k<<<(9*64*128+255)/256, 256, 0, stream>>>(w_[1], Wp1, 64, 128);
    pack_k<<<(9*128*128+255)/256, 256, 0, stream>>>(w_[2], Wp2, 128, 128);
    pack_k<<<(9*128*64+255)/256, 256, 0, stream>>>(w_[3], Wp3, 128, 64);
    packW_k<<<512, 256, 0, stream>>>(lW0,           Wx0p, 256);
    packW_k<<<256, 256, 0, stream>>>(lW0 + 256*512, Wh0p, 128);
    packW_k<<<256, 256, 0, stream>>>(lW1,           Wx1p, 128);
    packW_k<<<256, 256, 0, stream>>>(lW1 + 128*512, Wh1p, 128);
    packWoT_k<<<19, 256, 0, stream>>>(Wout, WoT);
    bn_k<<<1,128,0,stream>>>(cb_[1],g_[1],bb_[1],mm_[1],mv_[1], bns+0,   bns+128, 128);
    bn_k<<<1,128,0,stream>>>(cb_[2],g_[2],bb_[2],mm_[2],mv_[2], bns+256, bns+384, 128);
    bn_k<<<1,64 ,0,stream>>>(cb_[3],g_[3],bb_[3],mm_[3],mv_[3], bns+512, bns+576, 64);
    bn_k<<<1,64 ,0,stream>>>(cb_[0],g_[0],bb_[0],mm_[0],mv_[0], bns+640, bns+704, 64);

    const int nc = 256 / Bc;
    for (int bc=0; bc<nc; bc++){
        int bbase = bc*Bc;
        conv0_k<<<(Bc*2700+255)/256, 256, 0, stream>>>(x, w_[0], bns+640, bns+704, A, bbase, Bc*2700);
        convmf_k<64,128,30,90><<<dim3(6,4,Bc), 256, 0, stream>>>(A, Wp1, bns+0, bns+128, Bb);
        convmf_k<128,128,15,45><<<dim3(3,2,Bc), 256, 0, stream>>>(Bb, Wp2, bns+256, bns+384, C);
        convmf_k<128,64,8,23><<<dim3(2,1,Bc), 256, 0, stream>>>(C, Wp3, bns+512, bns+576,
                                                                F + (size_t)bbase*3072);
    }
    gemmrow_k<256,0><<<48, 256, 0, stream>>>(F, Wx0p, lb0, XP);
    lstm0_k<<<256, 512, 0, stream>>>(XP, Wh0p, h0g);
    gemmrow_k<128,1><<<48, 256, 0, stream>>>(h0g, Wx1p, lb1, ZP1);
    lstm1_k<<<256, 512, 0, stream>>>(ZP1, Wh1p, WoT, bout, out);
}